// Round 6
// baseline (456.538 us; speedup 1.0000x reference)
//
#include <hip/hip_runtime.h>
#include <hip/hip_bf16.h>
#include <cstdint>
#include <cstddef>

// Shapes (fixed): B=8, S=512, E=H=2048.
#define RTOT 4096      // B*S rows
#define DIM  2048
#define NCAT 6144      // f | c | g column sections
#define NCHUNK 32      // scan chunks
#define TCHUNK 16      // timesteps per chunk
#define FRAG  1024     // bytes per 16x64 i8 fragment
#define KT    32       // k-tiles (2048/64)

typedef __attribute__((ext_vector_type(4))) int int4v;

__device__ __forceinline__ float fast_sigmoid(float z) {
    return __builtin_amdgcn_rcpf(1.0f + __expf(-z));
}
__device__ __forceinline__ unsigned short f2h(float f) {
    union { _Float16 h; unsigned short u; } v; v.h = (_Float16)f; return v.u;
}
__device__ __forceinline__ float h2f(unsigned short u) {
    union { _Float16 h; unsigned short u; } v; v.u = u; return (float)v.h;
}

// ---------------------------------------------------------------------------
// prep_all: pack ALL GEMM operands in MFMA-fragment-major layout:
//   P[tile][ktile][lane][16B], lane=(k16)*16+(row%16), bytes = k%16.
//   blocks [0,3072)    : WcatT -> PWcat (transpose + i8 + pack)
//   blocks [3072,4096) : W_g   -> PWg   (i8 + pack, row-major is B^T)
//   blocks [4096,8192) : rmsnorm/act_quant -> PXq, PQ1, PQ2 (packed), Xh fp16
__global__ __launch_bounds__(256) void prep_all(
    const float* __restrict__ x, const float* __restrict__ scale,
    const float* __restrict__ Wf, const float* __restrict__ Wc,
    const float* __restrict__ Wg,
    signed char* __restrict__ PWcat, signed char* __restrict__ PWg,
    signed char* __restrict__ PXq, signed char* __restrict__ PQ1,
    signed char* __restrict__ PQ2, unsigned short* __restrict__ Xh,
    float* __restrict__ s_arr, float* __restrict__ s1_arr)
{
    __shared__ __align__(16) char smem[4224];
    int bid = blockIdx.x;
    int tid = threadIdx.x;
    if (bid < 3072) {
        // 64(j) x 64(k) tile of Wsel -> 4 packed fragments
        signed char (*tile)[65] = (signed char(*)[65])smem;
        int j0 = (bid % 96) * 64;
        int k0 = (bid / 96) * 64;
        const float* W = (j0 < 2048) ? Wf : (j0 < 4096) ? Wc : Wg;
        int jb = j0 & 2047;
        int c  = tid & 63;
        int rr = tid >> 6;
#pragma unroll
        for (int p = 0; p < 16; ++p) {
            int kl = p * 4 + rr;
            tile[kl][c] = (signed char)(int)W[(size_t)(k0 + kl) * DIM + jb + c];
        }
        __syncthreads();
        int f = tid >> 6, l = tid & 63;
        int lr = l & 15, lq = l >> 4;
        signed char frag[16];
#pragma unroll
        for (int b = 0; b < 16; ++b) frag[b] = tile[lq * 16 + b][f * 16 + lr];
        signed char* dst = PWcat +
            ((size_t)((j0 >> 4) + f) * KT + (k0 >> 6)) * FRAG + l * 16;
        *(int4v*)dst = *(int4v*)frag;
    } else if (bid < 4096) {
        // W_g row-major = B^T; pack 4 fragments per block
        int fid = (bid - 3072) * 4 + (tid >> 6);
        int nt = fid >> 5, kt = fid & 31;
        int l = tid & 63, lr = l & 15, lq = l >> 4;
        const float* src = Wg + (size_t)(nt * 16 + lr) * DIM + kt * 64 + lq * 16;
        signed char frag[16];
#pragma unroll
        for (int p = 0; p < 4; ++p) {
            float4 v = *(const float4*)(src + p * 4);
            frag[p * 4 + 0] = (signed char)(int)v.x;
            frag[p * 4 + 1] = (signed char)(int)v.y;
            frag[p * 4 + 2] = (signed char)(int)v.z;
            frag[p * 4 + 3] = (signed char)(int)v.w;
        }
        *(int4v*)(PWg + (size_t)fid * FRAG + l * 16) = *(int4v*)frag;
    } else {
        float* red = (float*)smem;
        float* tot = (float*)(smem + 64);
        int row = bid - 4096;
        const float* xr = x + (size_t)row * DIM + tid * 8;
        const float* sr = scale + tid * 8;
        float4 a0 = *(const float4*)(xr);
        float4 a1 = *(const float4*)(xr + 4);
        float4 c0 = *(const float4*)(sr);
        float4 c1 = *(const float4*)(sr + 4);
        float xs[8] = {a0.x, a0.y, a0.z, a0.w, a1.x, a1.y, a1.z, a1.w};
        float sc[8] = {c0.x, c0.y, c0.z, c0.w, c1.x, c1.y, c1.z, c1.w};
        float sum = 0.f, mx2 = 0.f;
#pragma unroll
        for (int i = 0; i < 8; ++i) {
            sum += xs[i] * xs[i];
            mx2 = fmaxf(mx2, fabsf(xs[i]));
        }
#pragma unroll
        for (int off = 32; off > 0; off >>= 1) {
            sum += __shfl_down(sum, off);
            mx2 = fmaxf(mx2, __shfl_down(mx2, off));
        }
        int lane = tid & 63, wv = tid >> 6;
        if (lane == 0) { red[wv] = sum; red[4 + wv] = mx2; }
        __syncthreads();
        if (tid == 0) {
            tot[0] = red[0] + red[1] + red[2] + red[3];
            tot[1] = fmaxf(fmaxf(red[4], red[5]), fmaxf(red[6], red[7]));
        }
        __syncthreads();
        float rms = 1.0f / sqrtf(tot[0] * (1.0f / 2048.0f) + 1e-5f);
        float y[8]; float mx = 0.f;
#pragma unroll
        for (int i = 0; i < 8; ++i) {
            y[i] = (xs[i] * rms) * sc[i];
            mx = fmaxf(mx, fabsf(y[i]));
        }
#pragma unroll
        for (int off = 32; off > 0; off >>= 1) mx = fmaxf(mx, __shfl_down(mx, off));
        if (lane == 0) red[8 + wv] = mx;
        __syncthreads();
        if (tid == 0)
            tot[2] = fmaxf(fmaxf(red[8], red[9]), fmaxf(red[10], red[11]));
        __syncthreads();
        float s = 127.0f / (tot[2] + 1e-5f);
        s = fminf(fmaxf(s, 0.001f), 1000.0f);
        float s1 = 127.0f / (tot[1] + 1e-5f);
        float inv_s1 = 1.0f / s1;
        if (tid == 0) { s_arr[row] = s; s1_arr[row] = s1; }
        signed char q8[8], q1b[8], q2b[8];
        unsigned short hx[8];
#pragma unroll
        for (int i = 0; i < 8; ++i) {
            float q = fminf(fmaxf(rintf(s * y[i]), -128.f), 127.f);
            q8[i] = (signed char)(int)q;
            float qq1 = fminf(fmaxf(rintf(s1 * xs[i]), -128.f), 127.f);
            q1b[i] = (signed char)(int)qq1;
            float r = xs[i] - qq1 * inv_s1;
            float qq2 = fminf(fmaxf(rintf(s1 * 256.f * r), -128.f), 127.f);
            q2b[i] = (signed char)(int)qq2;
            hx[i] = f2h(xs[i]);
        }
        // packed offset: e = tid*8 -> ktile=tid>>3, lq=(tid>>1)&3, b0=(tid&1)*8
        size_t off = ((size_t)(row >> 4) * KT + (tid >> 3)) * FRAG
                   + ((tid >> 1) & 3) * 256 + (row & 15) * 16 + (tid & 1) * 8;
        *(int2*)(PXq + off) = *(int2*)q8;
        *(int2*)(PQ1 + off) = *(int2*)q1b;
        *(int2*)(PQ2 + off) = *(int2*)q2b;
        *(int4v*)(Xh + (size_t)row * DIM + tid * 8) = *(int4v*)hx;
    }
}

// ---------------------------------------------------------------------------
// gemm_all: LDS-free. Every wave owns its own output tile; A/B fragments are
// read straight from the packed buffers with global_load_dwordx4 (1KB/wave,
// fully coalesced). No barriers anywhere -> compiler pipelines loads with
// vmcnt(N); register ping-pong prefetch gives one extra K-iter of latency
// cover. 3:2 fcg:cg interleave keeps both block types co-resident.
__global__ __launch_bounds__(256) void gemm_all(
    const signed char* __restrict__ PXq, const signed char* __restrict__ PWcat,
    const signed char* __restrict__ PQ1, const signed char* __restrict__ PQ2,
    const signed char* __restrict__ PWg, const unsigned short* __restrict__ Xh,
    const float* __restrict__ s_arr, const float* __restrict__ s1_arr,
    const float* __restrict__ b_f, const float* __restrict__ b_c,
    const float* __restrict__ b_g,
    unsigned short* __restrict__ FCG, unsigned short* __restrict__ U,
    unsigned short* __restrict__ V)
{
    int bid = blockIdx.x;
    int grp = bid / 5, r5 = bid % 5;
    int tid = threadIdx.x;
    int lane = tid & 63, wv = tid >> 6;
    int lr = lane & 15, lq = lane >> 4;

    if (r5 < 3) {
        // ---- fcg: wave tile 64x64 ----
        int wt = (grp * 3 + r5) * 4 + wv;        // 0..6143
        int m64 = wt / 96, n64 = wt % 96;
        int m0 = m64 * 64, n0 = n64 * 64;
        const signed char* Ab = PXq + (size_t)(m64 * 4) * (KT * FRAG) + lane * 16;
        const signed char* Bb = PWcat + (size_t)(n64 * 4) * (KT * FRAG) + lane * 16;

        int4v acc[4][4] = {};
        int4v a0[4], b0[4], a1[4], b1[4];
#pragma unroll
        for (int i = 0; i < 4; ++i) {
            a0[i] = *(const int4v*)(Ab + i * (KT * FRAG));
            b0[i] = *(const int4v*)(Bb + i * (KT * FRAG));
        }
        for (int kt = 0; kt < KT; kt += 2) {
#pragma unroll
            for (int i = 0; i < 4; ++i) {
                a1[i] = *(const int4v*)(Ab + i * (KT * FRAG) + (kt + 1) * FRAG);
                b1[i] = *(const int4v*)(Bb + i * (KT * FRAG) + (kt + 1) * FRAG);
            }
#pragma unroll
            for (int i = 0; i < 4; ++i)
#pragma unroll
                for (int j = 0; j < 4; ++j)
                    acc[i][j] = __builtin_amdgcn_mfma_i32_16x16x64_i8(
                        a0[i], b0[j], acc[i][j], 0, 0, 0);
            int ktn = (kt + 2) & (KT - 1);       // wraps to 0 once, unused
#pragma unroll
            for (int i = 0; i < 4; ++i) {
                a0[i] = *(const int4v*)(Ab + i * (KT * FRAG) + ktn * FRAG);
                b0[i] = *(const int4v*)(Bb + i * (KT * FRAG) + ktn * FRAG);
            }
#pragma unroll
            for (int i = 0; i < 4; ++i)
#pragma unroll
                for (int j = 0; j < 4; ++j)
                    acc[i][j] = __builtin_amdgcn_mfma_i32_16x16x64_i8(
                        a1[i], b1[j], acc[i][j], 0, 0, 0);
        }
#pragma unroll
        for (int i = 0; i < 4; ++i) {
            float rinv[4];
#pragma unroll
            for (int r = 0; r < 4; ++r)
                rinv[r] = __builtin_amdgcn_rcpf(s_arr[m0 + i * 16 + lq * 4 + r]);
#pragma unroll
            for (int j = 0; j < 4; ++j) {
                int gcol = n0 + j * 16 + lr;
                int sec = gcol >> 11;
                int jj = gcol & 2047;
                float bias = (sec == 0) ? b_f[jj] : (sec == 1) ? b_c[jj] : b_g[jj];
#pragma unroll
                for (int r = 0; r < 4; ++r) {
                    int grow = m0 + i * 16 + lq * 4 + r;
                    float z = fmaf((float)acc[i][j][r], rinv[r], bias);
                    float sg = fast_sigmoid(z);
                    FCG[(size_t)grow * NCAT + gcol] = f2h((sec == 1) ? z * sg : sg);
                }
            }
        }
    } else {
        // ---- cg: wave tile 32x64, two i8 planes ----
        int wt = (grp * 2 + (r5 - 3)) * 4 + wv;  // 0..4095
        int m32 = wt >> 5, n64 = wt & 31;
        int m0 = m32 * 32, n0 = n64 * 64;
        const signed char* A1b = PQ1 + (size_t)(m32 * 2) * (KT * FRAG) + lane * 16;
        const signed char* A2b = PQ2 + (size_t)(m32 * 2) * (KT * FRAG) + lane * 16;
        const signed char* Bb  = PWg + (size_t)(n64 * 4) * (KT * FRAG) + lane * 16;

        int4v acc1[2][4] = {};
        int4v acc2[2][4] = {};
        int4v p0[4], b0[4], p1[4], b1[4];   // p = {a1[0],a1[1],a2[0],a2[1]}
#pragma unroll
        for (int i = 0; i < 2; ++i) {
            p0[i]     = *(const int4v*)(A1b + i * (KT * FRAG));
            p0[2 + i] = *(const int4v*)(A2b + i * (KT * FRAG));
        }
#pragma unroll
        for (int j = 0; j < 4; ++j) b0[j] = *(const int4v*)(Bb + j * (KT * FRAG));
        for (int kt = 0; kt < KT; kt += 2) {
#pragma unroll
            for (int i = 0; i < 2; ++i) {
                p1[i]     = *(const int4v*)(A1b + i * (KT * FRAG) + (kt + 1) * FRAG);
                p1[2 + i] = *(const int4v*)(A2b + i * (KT * FRAG) + (kt + 1) * FRAG);
            }
#pragma unroll
            for (int j = 0; j < 4; ++j)
                b1[j] = *(const int4v*)(Bb + j * (KT * FRAG) + (kt + 1) * FRAG);
#pragma unroll
            for (int i = 0; i < 2; ++i)
#pragma unroll
                for (int j = 0; j < 4; ++j) {
                    acc1[i][j] = __builtin_amdgcn_mfma_i32_16x16x64_i8(
                        p0[i], b0[j], acc1[i][j], 0, 0, 0);
                    acc2[i][j] = __builtin_amdgcn_mfma_i32_16x16x64_i8(
                        p0[2 + i], b0[j], acc2[i][j], 0, 0, 0);
                }
            int ktn = (kt + 2) & (KT - 1);
#pragma unroll
            for (int i = 0; i < 2; ++i) {
                p0[i]     = *(const int4v*)(A1b + i * (KT * FRAG) + ktn * FRAG);
                p0[2 + i] = *(const int4v*)(A2b + i * (KT * FRAG) + ktn * FRAG);
            }
#pragma unroll
            for (int j = 0; j < 4; ++j)
                b0[j] = *(const int4v*)(Bb + j * (KT * FRAG) + ktn * FRAG);
#pragma unroll
            for (int i = 0; i < 2; ++i)
#pragma unroll
                for (int j = 0; j < 4; ++j) {
                    acc1[i][j] = __builtin_amdgcn_mfma_i32_16x16x64_i8(
                        p1[i], b1[j], acc1[i][j], 0, 0, 0);
                    acc2[i][j] = __builtin_amdgcn_mfma_i32_16x16x64_i8(
                        p1[2 + i], b1[j], acc2[i][j], 0, 0, 0);
                }
        }
#pragma unroll
        for (int i = 0; i < 2; ++i) {
            float rinv[4];
#pragma unroll
            for (int r = 0; r < 4; ++r)
                rinv[r] = __builtin_amdgcn_rcpf(s1_arr[m0 + i * 16 + lq * 4 + r]);
#pragma unroll
            for (int j = 0; j < 4; ++j) {
                int gcol = n0 + j * 16 + lr;
#pragma unroll
                for (int r = 0; r < 4; ++r) {
                    int grow = m0 + i * 16 + lq * 4 + r;
                    size_t go = (size_t)grow * DIM + gcol;
                    float zs = (float)acc1[i][j][r] + (float)acc2[i][j][r] * (1.f / 256.f);
                    float cg = fast_sigmoid(zs * rinv[r]);
                    float xv = h2f(Xh[go]);
                    U[go] = f2h(cg * xv);
                    V[go] = f2h(1.f - cg);
                }
            }
        }
    }
}

// ---------------------------------------------------------------------------
// Scan phase 1: 2 chains/thread, 16-step chunks.
__global__ __launch_bounds__(256) void scan_partial(
    const unsigned short* __restrict__ FCG, const unsigned short* __restrict__ U,
    const unsigned short* __restrict__ V, float4* __restrict__ PQ4)
{
    int tp = blockIdx.x * 256 + threadIdx.x;   // pair 0..1023
    int c = blockIdx.y;
    int b = blockIdx.z;
    int h0 = tp * 2;
    size_t r0 = (size_t)(b * 512 + c * TCHUNK);
    const unsigned short* fp = FCG + r0 * NCAT + h0;
    const unsigned short* up = U + r0 * DIM + h0;
    const unsigned short* vp = V + r0 * DIM + h0;
    float P0 = 1.f, Q0 = 0.f, P1 = 1.f, Q1v = 0.f;
#pragma unroll 4
    for (int t = 0; t < TCHUNK; ++t) {
        unsigned fw = *(const unsigned*)(fp);
        unsigned cw = *(const unsigned*)(fp + 2048);
        unsigned uw = *(const unsigned*)(up);
        unsigned vw = *(const unsigned*)(vp);
        float f0 = h2f(fw & 0xffff), f1 = h2f(fw >> 16);
        float c0 = h2f(cw & 0xffff), c1 = h2f(cw >> 16);
        float u0 = h2f(uw & 0xffff), u1 = h2f(uw >> 16);
        float v0 = h2f(vw & 0xffff), v1 = h2f(vw >> 16);
        float A0 = v0 * f0, A1 = v1 * f1;
        float B0 = fmaf(v0 * (1.f - f0), c0, u0);
        float B1 = fmaf(v1 * (1.f - f1), c1, u1);
        P0 = A0 * P0; Q0 = fmaf(A0, Q0, B0);
        P1 = A1 * P1; Q1v = fmaf(A1, Q1v, B1);
        fp += NCAT; up += DIM; vp += DIM;
    }
    float4 o; o.x = P0; o.y = Q0; o.z = P1; o.w = Q1v;
    PQ4[(size_t)c * 8192 + b * 1024 + tp] = o;
}

// Scan phase 2: recombine summaries for chunk-entry h, replay, emit o_t.
__global__ __launch_bounds__(256) void scan_final(
    const unsigned short* __restrict__ FCG, const unsigned short* __restrict__ U,
    const unsigned short* __restrict__ V, const float4* __restrict__ PQ4,
    float* __restrict__ out)
{
    int tp = blockIdx.x * 256 + threadIdx.x;
    int c = blockIdx.y;
    int b = blockIdx.z;
    int h0 = tp * 2;
    float h0s = 0.f, h1s = 0.f;
    for (int cc = 0; cc < c; ++cc) {
        float4 pq = PQ4[(size_t)cc * 8192 + b * 1024 + tp];
        h0s = fmaf(pq.x, h0s, pq.y);
        h1s = fmaf(pq.z, h1s, pq.w);
    }
    size_t r0 = (size_t)(b * 512 + c * TCHUNK);
    const unsigned short* fp = FCG + r0 * NCAT + h0;
    const unsigned short* up = U + r0 * DIM + h0;
    const unsigned short* vp = V + r0 * DIM + h0;
    float* op = out + r0 * DIM + h0;
#pragma unroll 4
    for (int t = 0; t < TCHUNK; ++t) {
        unsigned fw = *(const unsigned*)(fp);
        unsigned cw = *(const unsigned*)(fp + 2048);
        unsigned gw = *(const unsigned*)(fp + 4096);
        unsigned uw = *(const unsigned*)(up);
        unsigned vw = *(const unsigned*)(vp);
        float f0 = h2f(fw & 0xffff), f1 = h2f(fw >> 16);
        float c0 = h2f(cw & 0xffff), c1 = h2f(cw >> 16);
        float g0 = h2f(gw & 0xffff), g1 = h2f(gw >> 16);
        float u0 = h2f(uw & 0xffff), u1 = h2f(uw >> 16);
        float v0 = h2f(vw & 0xffff), v1 = h2f(vw >> 16);
        float hn0 = f0 * h0s + (1.f - f0) * c0;
        float hn1 = f1 * h1s + (1.f - f1) * c1;
        float2 ov; ov.x = g0 * hn0; ov.y = g1 * hn1;
        *(float2*)op = ov;
        h0s = fmaf(v0, hn0, u0);
        h1s = fmaf(v1, hn1, u1);
        fp += NCAT; up += DIM; vp += DIM; op += DIM;
    }
}

// ---------------------------------------------------------------------------
extern "C" void kernel_launch(void* const* d_in, const int* in_sizes, int n_in,
                              void* d_out, int out_size, void* d_ws, size_t ws_size,
                              hipStream_t stream) {
    const float* x     = (const float*)d_in[0];
    const float* rmssc = (const float*)d_in[1];
    const float* W_f   = (const float*)d_in[2];
    const float* W_c   = (const float*)d_in[3];
    const float* W_g   = (const float*)d_in[4];
    const float* b_f   = (const float*)d_in[5];
    const float* b_c   = (const float*)d_in[6];
    const float* b_g   = (const float*)d_in[7];
    float* out = (float*)d_out;

    char* ws = (char*)d_ws;
    size_t off = 0;
    auto alloc = [&](size_t bytes) -> void* {
        void* p = ws + off;
        off += (bytes + 255) & ~(size_t)255;
        return p;
    };
    signed char* PWcat = (signed char*)alloc((size_t)NCAT * DIM);
    signed char* PWg   = (signed char*)alloc((size_t)DIM * DIM);
    signed char* PXq   = (signed char*)alloc((size_t)RTOT * DIM);
    signed char* PQ1   = (signed char*)alloc((size_t)RTOT * DIM);
    signed char* PQ2   = (signed char*)alloc((size_t)RTOT * DIM);
    unsigned short* Xh = (unsigned short*)alloc((size_t)RTOT * DIM * 2);
    float* s_arr       = (float*)alloc((size_t)RTOT * 4);
    float* s1_arr      = (float*)alloc((size_t)RTOT * 4);
    unsigned short* FCG = (unsigned short*)alloc((size_t)RTOT * NCAT * 2);
    unsigned short* U   = (unsigned short*)alloc((size_t)RTOT * DIM * 2);
    unsigned short* V   = (unsigned short*)alloc((size_t)RTOT * DIM * 2);
    float4* PQ4        = (float4*)alloc((size_t)NCHUNK * 8192 * 16);

    hipLaunchKernelGGL(prep_all, dim3(8192), dim3(256), 0, stream,
                       x, rmssc, W_f, W_c, W_g, PWcat, PWg, PXq, PQ1, PQ2,
                       Xh, s_arr, s1_arr);
    hipLaunchKernelGGL(gemm_all, dim3(2560), dim3(256), 0, stream,
                       PXq, PWcat, PQ1, PQ2, PWg, Xh, s_arr, s1_arr,
                       b_f, b_c, b_g, FCG, U, V);
    hipLaunchKernelGGL(scan_partial, dim3(4, NCHUNK, 8), dim3(256), 0, stream,
                       FCG, U, V, PQ4);
    hipLaunchKernelGGL(scan_final, dim3(4, NCHUNK, 8), dim3(256), 0, stream,
                       FCG, U, V, PQ4, out);
}

// Round 7
// 328.214 us; speedup vs baseline: 1.3910x; 1.3910x over previous
//
#include <hip/hip_runtime.h>
#include <hip/hip_bf16.h>
#include <cstdint>
#include <cstddef>

// Shapes (fixed): B=8, S=512, E=H=2048.
#define RTOT 4096      // B*S rows
#define DIM  2048
#define NCAT 6144      // f | c | g sections in WcatT
#define NCHUNK 32      // scan chunks
#define TCHUNK 16      // timesteps per chunk

typedef __attribute__((ext_vector_type(4))) int int4v;

__device__ __forceinline__ float fast_sigmoid(float z) {
    return __builtin_amdgcn_rcpf(1.0f + __expf(-z));
}
__device__ __forceinline__ unsigned short f2h(float f) {
    union { _Float16 h; unsigned short u; } v; v.h = (_Float16)f; return v.u;
}
__device__ __forceinline__ float h2f(unsigned short u) {
    union { _Float16 h; unsigned short u; } v; v.u = u; return (float)v.h;
}
__device__ __forceinline__ unsigned pack2(float a, float b) {
    return (unsigned)f2h(a) | ((unsigned)f2h(b) << 16);
}

// global -> LDS DMA, 16B/lane; dest = wave-uniform base + lane*16.
#define GLDS(gp, lp) __builtin_amdgcn_global_load_lds( \
    (__attribute__((address_space(1))) const void*)(gp), \
    (__attribute__((address_space(3))) void*)(lp), 16, 0, 0)

// XOR chunk swizzle (0 conflicts, verified r2-r4): LDS[r][s] = G[r][s^((r>>1)&3)]
__device__ __forceinline__ int4v frag_ld(const signed char* lds, int R, int lq) {
    return *(const int4v*)(lds + R * 64 + ((lq ^ ((R >> 1) & 3)) * 16));
}

// ---------------------------------------------------------------------------
// prep_all (r4 version): [0,3072) WcatT transpose->i8; [3072,4096) Wg cast;
// [4096,8192) rmsnorm/act_quant -> Xq,Q1,Q2 (row-major) + scales.
__global__ __launch_bounds__(256) void prep_all(
    const float* __restrict__ x, const float* __restrict__ scale,
    const float* __restrict__ Wf, const float* __restrict__ Wc,
    const float* __restrict__ Wg,
    signed char* __restrict__ WcatT, signed char* __restrict__ Wgb,
    signed char* __restrict__ Xq, signed char* __restrict__ Q1,
    signed char* __restrict__ Q2, float* __restrict__ s_arr,
    float* __restrict__ s1_arr)
{
    __shared__ __align__(16) char smem[4224];
    int bid = blockIdx.x;
    int tid = threadIdx.x;
    if (bid < 3072) {
        signed char (*tile)[65] = (signed char(*)[65])smem;
        int j0 = (bid % 96) * 64;
        int k0 = (bid / 96) * 64;
        const float* W = (j0 < 2048) ? Wf : (j0 < 4096) ? Wc : Wg;
        int jb = j0 & 2047;
        int c  = tid & 63;
        int rr = tid >> 6;
#pragma unroll
        for (int p = 0; p < 16; ++p) {
            int kl = p * 4 + rr;
            tile[kl][c] = (signed char)(int)W[(size_t)(k0 + kl) * DIM + jb + c];
        }
        __syncthreads();
#pragma unroll
        for (int p = 0; p < 16; ++p) {
            int jl = p * 4 + rr;
            WcatT[(size_t)(j0 + jl) * DIM + k0 + c] = tile[c][jl];
        }
    } else if (bid < 4096) {
        int idx = (bid - 3072) * 4096 + tid * 16;
#pragma unroll
        for (int p = 0; p < 4; ++p) {
            float4 v = *(const float4*)(Wg + idx + p * 4);
            char4 o;
            o.x = (signed char)(int)v.x; o.y = (signed char)(int)v.y;
            o.z = (signed char)(int)v.z; o.w = (signed char)(int)v.w;
            *(char4*)(Wgb + idx + p * 4) = o;
        }
    } else {
        float* red = (float*)smem;
        float* tot = (float*)(smem + 64);
        int row = bid - 4096;
        const float* xr = x + (size_t)row * DIM + tid * 8;
        const float* sr = scale + tid * 8;
        float4 a0 = *(const float4*)(xr);
        float4 a1 = *(const float4*)(xr + 4);
        float4 c0 = *(const float4*)(sr);
        float4 c1 = *(const float4*)(sr + 4);
        float xs[8] = {a0.x, a0.y, a0.z, a0.w, a1.x, a1.y, a1.z, a1.w};
        float sc[8] = {c0.x, c0.y, c0.z, c0.w, c1.x, c1.y, c1.z, c1.w};
        float sum = 0.f, mx2 = 0.f;
#pragma unroll
        for (int i = 0; i < 8; ++i) {
            sum += xs[i] * xs[i];
            mx2 = fmaxf(mx2, fabsf(xs[i]));
        }
#pragma unroll
        for (int off = 32; off > 0; off >>= 1) {
            sum += __shfl_down(sum, off);
            mx2 = fmaxf(mx2, __shfl_down(mx2, off));
        }
        int lane = tid & 63, wv = tid >> 6;
        if (lane == 0) { red[wv] = sum; red[4 + wv] = mx2; }
        __syncthreads();
        if (tid == 0) {
            tot[0] = red[0] + red[1] + red[2] + red[3];
            tot[1] = fmaxf(fmaxf(red[4], red[5]), fmaxf(red[6], red[7]));
        }
        __syncthreads();
        float rms = 1.0f / sqrtf(tot[0] * (1.0f / 2048.0f) + 1e-5f);
        float y[8]; float mx = 0.f;
#pragma unroll
        for (int i = 0; i < 8; ++i) {
            y[i] = (xs[i] * rms) * sc[i];
            mx = fmaxf(mx, fabsf(y[i]));
        }
#pragma unroll
        for (int off = 32; off > 0; off >>= 1) mx = fmaxf(mx, __shfl_down(mx, off));
        if (lane == 0) red[8 + wv] = mx;
        __syncthreads();
        if (tid == 0)
            tot[2] = fmaxf(fmaxf(red[8], red[9]), fmaxf(red[10], red[11]));
        __syncthreads();
        float s = 127.0f / (tot[2] + 1e-5f);
        s = fminf(fmaxf(s, 0.001f), 1000.0f);
        float s1 = 127.0f / (tot[1] + 1e-5f);
        float inv_s1 = 1.0f / s1;
        if (tid == 0) { s_arr[row] = s; s1_arr[row] = s1; }
        signed char q8[8], q1b[8], q2b[8];
#pragma unroll
        for (int i = 0; i < 8; ++i) {
            float q = fminf(fmaxf(rintf(s * y[i]), -128.f), 127.f);
            q8[i] = (signed char)(int)q;
            float qq1 = fminf(fmaxf(rintf(s1 * xs[i]), -128.f), 127.f);
            q1b[i] = (signed char)(int)qq1;
            float r = xs[i] - qq1 * inv_s1;
            float qq2 = fminf(fmaxf(rintf(s1 * 256.f * r), -128.f), 127.f);
            q2b[i] = (signed char)(int)qq2;
        }
        size_t o = (size_t)row * DIM + tid * 8;
        *(int2*)(Xq + o) = *(int2*)q8;
        *(int2*)(Q1 + o) = *(int2*)q1b;
        *(int2*)(Q2 + o) = *(int2*)q2b;
    }
}

// ---------------------------------------------------------------------------
// gemm_cg (r4 structure): cg = sigmoid(((Q1+Q2/256)@Wg^T)/s1); writes packed
// UV[t][h] = (u=cg*x, v=1-cg) fp16x2. 64x128 tile, 4 waves of 32x64.
__global__ __launch_bounds__(256) void gemm_cg(
    const signed char* __restrict__ Q1, const signed char* __restrict__ Q2,
    const signed char* __restrict__ Wgb, const float* __restrict__ s1_arr,
    unsigned* __restrict__ UV)
{
    __shared__ __align__(16) signed char lds[32768];
    int cb = blockIdx.x;
    int m0 = (cb >> 4) * 64;
    int n0 = (cb & 15) * 128;
    int tid = threadIdx.x;
    int lane = tid & 63, wv = tid >> 6;
    int wm = (wv >> 1) * 32, wn = (wv & 1) * 64;
    int lr = lane & 15, lq = lane >> 4;
    int rA = lane >> 2;
    int gch = ((lane & 3) ^ ((lane >> 3) & 3)) * 16;
    const signed char* A1b = Q1 + (size_t)m0 * DIM;
    const signed char* A2b = Q2 + (size_t)m0 * DIM;
    const signed char* Bb  = Wgb + (size_t)n0 * DIM;
    int r1 = wv * 16 + rA;

    int4v acc1[2][4] = {};
    int4v acc2[2][4] = {};
    {
        GLDS(A1b + (size_t)r1 * DIM + gch, lds + wv * 1024);
        GLDS(A2b + (size_t)r1 * DIM + gch, lds + 4096 + wv * 1024);
#pragma unroll
        for (int it = 0; it < 2; ++it) {
            int region = wv + it * 4;
            GLDS(Bb + (size_t)(region * 16 + rA) * DIM + gch,
                 lds + 8192 + region * 1024);
        }
    }
    for (int k6 = 0; k6 < 32; ++k6) {
        const signed char* cur = lds + (k6 & 1) * 16384;
        signed char* nxt = lds + ((k6 + 1) & 1) * 16384;
        __syncthreads();
        if (k6 + 1 < 32) {
            int kt = (k6 + 1) * 64;
            GLDS(A1b + (size_t)r1 * DIM + kt + gch, nxt + wv * 1024);
            GLDS(A2b + (size_t)r1 * DIM + kt + gch, nxt + 4096 + wv * 1024);
#pragma unroll
            for (int it = 0; it < 2; ++it) {
                int region = wv + it * 4;
                GLDS(Bb + (size_t)(region * 16 + rA) * DIM + kt + gch,
                     nxt + 8192 + region * 1024);
            }
        }
        int4v bb[4];
#pragma unroll
        for (int j = 0; j < 4; ++j) bb[j] = frag_ld(cur + 8192, wn + j * 16 + lr, lq);
#pragma unroll
        for (int i = 0; i < 2; ++i) {
            int4v a1 = frag_ld(cur, wm + i * 16 + lr, lq);
            int4v a2 = frag_ld(cur + 4096, wm + i * 16 + lr, lq);
#pragma unroll
            for (int j = 0; j < 4; ++j) {
                acc1[i][j] = __builtin_amdgcn_mfma_i32_16x16x64_i8(
                    a1, bb[j], acc1[i][j], 0, 0, 0);
                acc2[i][j] = __builtin_amdgcn_mfma_i32_16x16x64_i8(
                    a2, bb[j], acc2[i][j], 0, 0, 0);
            }
        }
    }
#pragma unroll
    for (int i = 0; i < 2; ++i) {
        float rinv[4];
#pragma unroll
        for (int r = 0; r < 4; ++r)
            rinv[r] = __builtin_amdgcn_rcpf(s1_arr[m0 + wm + i * 16 + lq * 4 + r]);
#pragma unroll
        for (int j = 0; j < 4; ++j) {
            int gcol = n0 + wn + j * 16 + lr;
#pragma unroll
            for (int r = 0; r < 4; ++r) {
                int grow = m0 + wm + i * 16 + lq * 4 + r;
                size_t go = (size_t)grow * DIM + gcol;
                float zs = (float)acc1[i][j][r] + (float)acc2[i][j][r] * (1.f / 256.f);
                float cg = fast_sigmoid(zs * rinv[r]);
                float xv = ((float)Q1[go] + (float)Q2[go] * (1.f / 256.f)) * rinv[r];
                UV[go] = pack2(cg * xv, 1.f - cg);
            }
        }
    }
}

// ---------------------------------------------------------------------------
// gemm_fcg3: 64(t) x 64(h) x 3-section blocks, 3 waves (one section each).
// Epilogue folds the scan algebra: SC[t][h]=(A,B), SG[t][h]=(Gf,Gw), using
// UV from gemm_cg.  A=v*f, B=v*(1-f)*c+u, Gf=g*f, Gw=g*(1-f)*c.
__global__ __launch_bounds__(192) void gemm_fcg3(
    const signed char* __restrict__ Xq, const signed char* __restrict__ WcatT,
    const float* __restrict__ s_arr,
    const float* __restrict__ b_f, const float* __restrict__ b_c,
    const float* __restrict__ b_g, const unsigned* __restrict__ UV,
    unsigned* __restrict__ SC, unsigned* __restrict__ SG)
{
    __shared__ __align__(16) signed char lds[32768];
    int bid = blockIdx.x;
    int m0 = (bid >> 5) * 64;          // 64 m-tiles
    int n0 = (bid & 31) * 64;          // 32 h-tiles
    int tid = threadIdx.x;
    int lane = tid & 63, wv = tid >> 6;   // wv = section 0..2
    int lr = lane & 15, lq = lane >> 4;
    int rA = lane >> 2;
    int gch = ((lane & 3) ^ ((lane >> 3) & 3)) * 16;

    int4v acc[4][4] = {};
    // stage tile 0: regions 0-3 = A (Xq rows m0..m0+63), 4-15 = B
    // (WcatT rows sec*2048 + n0 + q*16, sec=(r-4)>>2, q=(r-4)&3)
    for (int r = wv; r < 16; r += 3) {
        const signed char* g = (r < 4)
            ? Xq + (size_t)(m0 + r * 16 + rA) * DIM
            : WcatT + (size_t)(((r - 4) >> 2) * 2048 + n0 + ((r - 4) & 3) * 16 + rA) * DIM;
        GLDS(g + gch, lds + r * 1024);
    }
    for (int k6 = 0; k6 < 32; ++k6) {
        const signed char* cur = lds + (k6 & 1) * 16384;
        signed char* nxt = lds + ((k6 + 1) & 1) * 16384;
        __syncthreads();
        if (k6 + 1 < 32) {
            int kt = (k6 + 1) * 64;
            for (int r = wv; r < 16; r += 3) {
                const signed char* g = (r < 4)
                    ? Xq + (size_t)(m0 + r * 16 + rA) * DIM
                    : WcatT + (size_t)(((r - 4) >> 2) * 2048 + n0 + ((r - 4) & 3) * 16 + rA) * DIM;
                GLDS(g + kt + gch, nxt + r * 1024);
            }
        }
        const signed char* Bsec = cur + 4096 + wv * 4096;
        int4v af[4], bb[4];
#pragma unroll
        for (int i = 0; i < 4; ++i) af[i] = frag_ld(cur, i * 16 + lr, lq);
#pragma unroll
        for (int j = 0; j < 4; ++j) bb[j] = frag_ld(Bsec, j * 16 + lr, lq);
#pragma unroll
        for (int i = 0; i < 4; ++i)
#pragma unroll
            for (int j = 0; j < 4; ++j)
                acc[i][j] = __builtin_amdgcn_mfma_i32_16x16x64_i8(
                    af[i], bb[j], acc[i][j], 0, 0, 0);
    }
    __syncthreads();   // all waves done reading staging LDS before overlay
    // compute section values -> LDS exchange (fp16), ex[sec][t][h]
    unsigned short* ex = (unsigned short*)lds;
    const float* bsel = (wv == 0) ? b_f : (wv == 1) ? b_c : b_g;
#pragma unroll
    for (int i = 0; i < 4; ++i) {
        float rinv[4];
#pragma unroll
        for (int r = 0; r < 4; ++r)
            rinv[r] = __builtin_amdgcn_rcpf(s_arr[m0 + i * 16 + lq * 4 + r]);
#pragma unroll
        for (int j = 0; j < 4; ++j) {
            int hl = j * 16 + lr;
            float bias = bsel[n0 + hl];
#pragma unroll
            for (int r = 0; r < 4; ++r) {
                int tl = i * 16 + lq * 4 + r;
                float z = fmaf((float)acc[i][j][r], rinv[r], bias);
                float sg = fast_sigmoid(z);
                ex[wv * 4096 + tl * 64 + hl] = f2h((wv == 1) ? z * sg : sg);
            }
        }
    }
    __syncthreads();
    // combine: A,B,Gf,Gw per (t,h)
    for (int idx = tid; idx < 4096; idx += 192) {
        int tl = idx >> 6, hl = idx & 63;
        float f = h2f(ex[tl * 64 + hl]);
        float c = h2f(ex[4096 + tl * 64 + hl]);
        float g = h2f(ex[8192 + tl * 64 + hl]);
        size_t go = (size_t)(m0 + tl) * DIM + n0 + hl;
        unsigned uv = UV[go];
        float u = h2f(uv & 0xffff), v = h2f(uv >> 16);
        float w = (1.f - f) * c;
        SC[go] = pack2(v * f, fmaf(v, w, u));
        SG[go] = pack2(g * f, g * w);
    }
}

// ---------------------------------------------------------------------------
// Scan phase 1: 2 chains/thread, ONE 8B load per t. h' = A h + B.
__global__ __launch_bounds__(256) void scan_partial(
    const unsigned* __restrict__ SC, float4* __restrict__ PQ4)
{
    int tp = blockIdx.x * 256 + threadIdx.x;   // h-pair 0..1023
    int c = blockIdx.y;
    int b = blockIdx.z;
    size_t r0 = (size_t)(b * 512 + c * TCHUNK);
    const uint2* scp = (const uint2*)(SC + r0 * DIM) + tp;
    float P0 = 1.f, Q0 = 0.f, P1 = 1.f, Q1v = 0.f;
#pragma unroll
    for (int t = 0; t < TCHUNK; ++t) {
        uint2 w = scp[t * (DIM / 2)];
        float A0 = h2f(w.x & 0xffff), B0 = h2f(w.x >> 16);
        float A1 = h2f(w.y & 0xffff), B1 = h2f(w.y >> 16);
        P0 = A0 * P0; Q0 = fmaf(A0, Q0, B0);
        P1 = A1 * P1; Q1v = fmaf(A1, Q1v, B1);
    }
    float4 o; o.x = P0; o.y = Q0; o.z = P1; o.w = Q1v;
    PQ4[(size_t)c * 8192 + b * 1024 + tp] = o;
}

// Scan phase 2: recombine chunk summaries, then o = Gf h + Gw ; h = A h + B.
__global__ __launch_bounds__(256) void scan_final(
    const unsigned* __restrict__ SC, const unsigned* __restrict__ SG,
    const float4* __restrict__ PQ4, float* __restrict__ out)
{
    int tp = blockIdx.x * 256 + threadIdx.x;
    int c = blockIdx.y;
    int b = blockIdx.z;
    float h0s = 0.f, h1s = 0.f;
    for (int cc = 0; cc < c; ++cc) {
        float4 pq = PQ4[(size_t)cc * 8192 + b * 1024 + tp];
        h0s = fmaf(pq.x, h0s, pq.y);
        h1s = fmaf(pq.z, h1s, pq.w);
    }
    size_t r0 = (size_t)(b * 512 + c * TCHUNK);
    const uint2* scp = (const uint2*)(SC + r0 * DIM) + tp;
    const uint2* sgp = (const uint2*)(SG + r0 * DIM) + tp;
    float* op = out + r0 * DIM + tp * 2;
#pragma unroll
    for (int t = 0; t < TCHUNK; ++t) {
        uint2 ws = scp[t * (DIM / 2)];
        uint2 wg = sgp[t * (DIM / 2)];
        float A0 = h2f(ws.x & 0xffff), B0 = h2f(ws.x >> 16);
        float A1 = h2f(ws.y & 0xffff), B1 = h2f(ws.y >> 16);
        float Gf0 = h2f(wg.x & 0xffff), Gw0 = h2f(wg.x >> 16);
        float Gf1 = h2f(wg.y & 0xffff), Gw1 = h2f(wg.y >> 16);
        float2 ov;
        ov.x = fmaf(Gf0, h0s, Gw0);
        ov.y = fmaf(Gf1, h1s, Gw1);
        *(float2*)(op + (size_t)t * DIM) = ov;
        h0s = fmaf(A0, h0s, B0);
        h1s = fmaf(A1, h1s, B1);
    }
}

// ---------------------------------------------------------------------------
extern "C" void kernel_launch(void* const* d_in, const int* in_sizes, int n_in,
                              void* d_out, int out_size, void* d_ws, size_t ws_size,
                              hipStream_t stream) {
    const float* x     = (const float*)d_in[0];
    const float* rmssc = (const float*)d_in[1];
    const float* W_f   = (const float*)d_in[2];
    const float* W_c   = (const float*)d_in[3];
    const float* W_g   = (const float*)d_in[4];
    const float* b_f   = (const float*)d_in[5];
    const float* b_c   = (const float*)d_in[6];
    const float* b_g   = (const float*)d_in[7];
    float* out = (float*)d_out;

    char* ws = (char*)d_ws;
    size_t off = 0;
    auto alloc = [&](size_t bytes) -> void* {
        void* p = ws + off;
        off += (bytes + 255) & ~(size_t)255;
        return p;
    };
    signed char* WcatT = (signed char*)alloc((size_t)NCAT * DIM);
    signed char* Wgb   = (signed char*)alloc((size_t)DIM * DIM);
    signed char* Xq    = (signed char*)alloc((size_t)RTOT * DIM);
    signed char* Q1    = (signed char*)alloc((size_t)RTOT * DIM);
    signed char* Q2    = (signed char*)alloc((size_t)RTOT * DIM);
    float* s_arr       = (float*)alloc((size_t)RTOT * 4);
    float* s1_arr      = (float*)alloc((size_t)RTOT * 4);
    unsigned* UV       = (unsigned*)alloc((size_t)RTOT * DIM * 4);
    unsigned* SC       = (unsigned*)alloc((size_t)RTOT * DIM * 4);
    unsigned* SG       = (unsigned*)alloc((size_t)RTOT * DIM * 4);
    float4* PQ4        = (float4*)alloc((size_t)NCHUNK * 8192 * 16);

    hipLaunchKernelGGL(prep_all, dim3(8192), dim3(256), 0, stream,
                       x, rmssc, W_f, W_c, W_g, WcatT, Wgb, Xq, Q1, Q2,
                       s_arr, s1_arr);
    hipLaunchKernelGGL(gemm_cg, dim3(1024), dim3(256), 0, stream,
                       Q1, Q2, Wgb, s1_arr, UV);
    hipLaunchKernelGGL(gemm_fcg3, dim3(2048), dim3(192), 0, stream,
                       Xq, WcatT, s_arr, b_f, b_c, b_g, UV, SC, SG);
    hipLaunchKernelGGL(scan_partial, dim3(4, NCHUNK, 8), dim3(256), 0, stream,
                       SC, PQ4);
    hipLaunchKernelGGL(scan_final, dim3(4, NCHUNK, 8), dim3(256), 0, stream,
                       SC, SG, PQ4, out);
}